// Round 3
// baseline (10060.670 us; speedup 1.0000x reference)
//
#include <hip/hip_runtime.h>

#define INPUT 64
#define HID 256
#define BATCH 128
#define TSTEPS 1000
#define KTOT 320            // 256 (h) + 64 (x)

typedef __bf16 bf16_t;
typedef float f32x4 __attribute__((ext_vector_type(4)));

// ---- ws layout (bytes) ----
#define WPACK_OFF   0
#define WPACK_BYTES (1024 * KTOT * 2)            // 655360
#define BIAS_OFF    (WPACK_OFF + WPACK_BYTES)
#define BIAS_BYTES  (1024 * 4)
#define EXCH_OFF    (BIAS_OFF + BIAS_BYTES)      // 16 slots x 2 parity x 16x128 bf16
#define EXCH_BYTES  (16 * 2 * 2048 * 2)
#define FLAG_OFF    (EXCH_OFF + EXCH_BYTES)      // 16 flags, 64B apart

// D(C) = A*B + C ; A,acc in VGPR ; B pinned in AGPR (forces weight residency)
#define MFMA_AB(acc, a, b) \
    asm("v_mfma_f32_16x16x32_bf16 %0, %1, %2, %0" : "+v"(acc) : "v"(a), "a"(b))

__global__ void lstm_prep(
    const float* __restrict__ Wii, const float* __restrict__ Wif,
    const float* __restrict__ Wig, const float* __restrict__ Wio,
    const float* __restrict__ Whi, const float* __restrict__ Whf,
    const float* __restrict__ Whg, const float* __restrict__ Who,
    const float* __restrict__ bii, const float* __restrict__ bif,
    const float* __restrict__ big, const float* __restrict__ bio,
    const float* __restrict__ bhi, const float* __restrict__ bhf,
    const float* __restrict__ bhg, const float* __restrict__ bho,
    bf16_t* __restrict__ wpack, float* __restrict__ bias,
    int* __restrict__ flags)
{
    int id = blockIdx.x * 256 + threadIdx.x;
    if (id < 1024 * KTOT) {
        int n = id / KTOT, k = id % KTOT;
        int g = n >> 8, j = n & 255;
        const float* Wh = (g == 0) ? Whi : (g == 1) ? Whf : (g == 2) ? Whg : Who;
        const float* Wi = (g == 0) ? Wii : (g == 1) ? Wif : (g == 2) ? Wig : Wio;
        float v = (k < HID) ? Wh[j * HID + k] : Wi[j * INPUT + (k - HID)];
        wpack[id] = (bf16_t)v;
    }
    if (id < 1024) {
        int g = id >> 8, j = id & 255;
        const float* bi = (g == 0) ? bii : (g == 1) ? bif : (g == 2) ? big : bio;
        const float* bh = (g == 0) ? bhi : (g == 1) ? bhf : (g == 2) ? bhg : bho;
        bias[id] = bi[j] + bh[j];
    }
    if (id < 16) flags[id * 16] = 0;
}

__device__ __forceinline__ float sigmoid_f(float v) {
    return 1.0f / (1.0f + __expf(-v));
}
__device__ __forceinline__ float tanh_f(float v) {
    return 1.0f - 2.0f / (__expf(2.0f * v) + 1.0f);
}

// 16 blocks: group = blockIdx&7 (pair b, b+8 -> same XCD), half = blockIdx>>3
__global__ __launch_bounds__(256, 1) void lstm_main(
    const float* __restrict__ x, const bf16_t* __restrict__ wpack,
    const float* __restrict__ bias_g, float* __restrict__ out,
    bf16_t* __restrict__ exch, int* __restrict__ flags)
{
    __shared__ bf16_t hx[16 * 136];      // own h half: [16][128] pad->136
    __shared__ bf16_t xb[2 * 16 * 72];   // x stage dbuf: [2][16][64] pad->72

    const int bid   = blockIdx.x;
    const int group = bid & 7;
    const int half  = bid >> 3;
    const int tid   = threadIdx.x;
    const int w     = tid >> 6;          // wave 0..3
    const int l     = tid & 63;
    const int col   = l & 15;
    const int kb    = l >> 4;            // 0..3
    const int jbase = w * 32;            // wave owns cols [w*32, w*32+32) of the half

    // ---- persistent weights: [gate][ntile][kslice] = 80 frags -> 320 AGPRs ----
    f32x4 bW[4][2][10];
#pragma unroll
    for (int gt = 0; gt < 4; ++gt)
#pragma unroll
        for (int n = 0; n < 2; ++n) {
            const int jglob = half * 128 + jbase + n * 16 + col;
            const bf16_t* wrow = wpack + (size_t)(gt * 256 + jglob) * KTOT;
#pragma unroll
            for (int ks = 0; ks < 10; ++ks)
                bW[gt][n][ks] = *(const f32x4*)(wrow + ks * 32 + kb * 8);
        }
#pragma unroll
    for (int gt = 0; gt < 4; ++gt)
#pragma unroll
        for (int n = 0; n < 2; ++n)
#pragma unroll
            for (int ks = 0; ks < 10; ++ks)
                asm volatile("" : "+a"(bW[gt][n][ks]));   // park in AGPRs now

    float bias_r[4][2];
#pragma unroll
    for (int gt = 0; gt < 4; ++gt)
#pragma unroll
        for (int n = 0; n < 2; ++n)
            bias_r[gt][n] = bias_g[gt * 256 + half * 128 + jbase + n * 16 + col];

    float c_st[2][4] = {{0.f, 0.f, 0.f, 0.f}, {0.f, 0.f, 0.f, 0.f}};

    const int me = group * 2 + half;
    const int pn = group * 2 + (1 - half);
    int* flag_me = flags + me * 16;
    int* flag_pn = flags + pn * 16;

    // prologue: stage x_0 into xb parity 0
    {
        int b = tid >> 4, i0 = (tid & 15) * 4;
        float4 v = *(const float4*)(x + (size_t)(group * 16 + b) * (TSTEPS * INPUT) + i0);
        bf16_t* d = xb + b * 72 + i0;
        d[0] = (bf16_t)v.x; d[1] = (bf16_t)v.y; d[2] = (bf16_t)v.z; d[3] = (bf16_t)v.w;
    }
    __syncthreads();

    for (int t = 0; t < TSTEPS; ++t) {
        const int par = t & 1;

        f32x4 acc[4][2];
#pragma unroll
        for (int gt = 0; gt < 4; ++gt)
#pragma unroll
            for (int n = 0; n < 2; ++n)
                acc[gt][n] = (f32x4){bias_r[gt][n], bias_r[gt][n], bias_r[gt][n], bias_r[gt][n]};

        // x-part (K slices 8,9)
        {
            const bf16_t* xrow = xb + par * 1152 + col * 72 + kb * 8;
            f32x4 a0 = *(const f32x4*)(xrow);
            f32x4 a1 = *(const f32x4*)(xrow + 32);
#pragma unroll
            for (int gt = 0; gt < 4; ++gt)
#pragma unroll
                for (int n = 0; n < 2; ++n) {
                    MFMA_AB(acc[gt][n], a0, bW[gt][n][8]);
                    MFMA_AB(acc[gt][n], a1, bW[gt][n][9]);
                }
        }
        // own h half (K slices half*4 .. half*4+3)
        if (t > 0) {
            f32x4 ah[4];
#pragma unroll
            for (int i = 0; i < 4; ++i)
                ah[i] = *(const f32x4*)(hx + col * 136 + i * 32 + kb * 8);
#pragma unroll
            for (int gt = 0; gt < 4; ++gt)
#pragma unroll
                for (int n = 0; n < 2; ++n)
#pragma unroll
                    for (int i = 0; i < 4; ++i)
                        MFMA_AB(acc[gt][n], ah[i], bW[gt][n][half * 4 + i]);
        }
        // stage x_{t+1} into other parity
        if (t + 1 < TSTEPS) {
            int b = tid >> 4, i0 = (tid & 15) * 4;
            float4 v = *(const float4*)(x + (size_t)(group * 16 + b) * (TSTEPS * INPUT) + (size_t)(t + 1) * INPUT + i0);
            bf16_t* d = xb + (par ^ 1) * 1152 + b * 72 + i0;
            d[0] = (bf16_t)v.x; d[1] = (bf16_t)v.y; d[2] = (bf16_t)v.z; d[3] = (bf16_t)v.w;
        }
        // partner h half (via L2 exchange)
        if (t > 0) {
            if (tid == 0) {
                while (__hip_atomic_load(flag_pn, __ATOMIC_ACQUIRE, __HIP_MEMORY_SCOPE_AGENT) < t) {}
            }
            __syncthreads();                               // (B2) partner h_{t-1} visible; hx reads done
            const bf16_t* bufR = exch + (size_t)(pn * 2 + ((t - 1) & 1)) * 2048;
            f32x4 ap[4];
#pragma unroll
            for (int i = 0; i < 4; ++i)
                ap[i] = *(const f32x4*)(bufR + col * 128 + i * 32 + kb * 8);
#pragma unroll
            for (int gt = 0; gt < 4; ++gt)
#pragma unroll
                for (int n = 0; n < 2; ++n)
#pragma unroll
                    for (int i = 0; i < 4; ++i)
                        MFMA_AB(acc[gt][n], ap[i], bW[gt][n][(1 - half) * 4 + i]);
        }

        // epilogue: gates -> c,h ; publish h
        bf16_t* bufW = exch + (size_t)(me * 2 + par) * 2048;
        float hv[2][4];
#pragma unroll
        for (int n = 0; n < 2; ++n)
#pragma unroll
            for (int r = 0; r < 4; ++r) {
                int be = kb * 4 + r;                       // batch row in group
                int jl = jbase + n * 16 + col;
                float gi = sigmoid_f(acc[0][n][r]);
                float gf = sigmoid_f(acc[1][n][r]);
                float gg = tanh_f(acc[2][n][r]);
                float go = sigmoid_f(acc[3][n][r]);
                float c  = gf * c_st[n][r] + gi * gg;
                c_st[n][r] = c;
                float h  = go * tanh_f(c);
                hv[n][r] = h;
                bf16_t hb = (bf16_t)h;
                hx[be * 136 + jl]   = hb;                  // own A for next step
                bufW[be * 128 + jl] = hb;                  // partner's A for next step
            }
        __syncthreads();                                   // (B3) hx + bufW stores drained
        if (tid == 0)
            __hip_atomic_store(flag_me, t + 1, __ATOMIC_RELEASE, __HIP_MEMORY_SCOPE_AGENT);
        // out stores AFTER release (drain overlaps next step)
#pragma unroll
        for (int n = 0; n < 2; ++n)
#pragma unroll
            for (int r = 0; r < 4; ++r) {
                int bg = group * 16 + kb * 4 + r;
                int jg = half * 128 + jbase + n * 16 + col;
                out[((size_t)bg * TSTEPS + t) * HID + jg] = hv[n][r];
                if (t == TSTEPS - 1) {
                    out[(size_t)BATCH * TSTEPS * HID + (size_t)bg * HID + jg] = hv[n][r];
                    out[(size_t)BATCH * TSTEPS * HID + (size_t)BATCH * HID + (size_t)bg * HID + jg] = c_st[n][r];
                }
            }
    }
}

extern "C" void kernel_launch(void* const* d_in, const int* in_sizes, int n_in,
                              void* d_out, int out_size, void* d_ws, size_t ws_size,
                              hipStream_t stream)
{
    (void)in_sizes; (void)n_in; (void)out_size; (void)ws_size;
    const float* x   = (const float*)d_in[0];
    const float* Wii = (const float*)d_in[1];
    const float* bii = (const float*)d_in[2];
    const float* Wif = (const float*)d_in[3];
    const float* bif = (const float*)d_in[4];
    const float* Wig = (const float*)d_in[5];
    const float* big = (const float*)d_in[6];
    const float* Wio = (const float*)d_in[7];
    const float* bio = (const float*)d_in[8];
    const float* Whi = (const float*)d_in[9];
    const float* bhi = (const float*)d_in[10];
    const float* Whf = (const float*)d_in[11];
    const float* bhf = (const float*)d_in[12];
    const float* Whg = (const float*)d_in[13];
    const float* bhg = (const float*)d_in[14];
    const float* Who = (const float*)d_in[15];
    const float* bho = (const float*)d_in[16];

    char* ws = (char*)d_ws;
    bf16_t* wpack = (bf16_t*)(ws + WPACK_OFF);
    float*  bias  = (float*)(ws + BIAS_OFF);
    bf16_t* exch  = (bf16_t*)(ws + EXCH_OFF);
    int*    flags = (int*)(ws + FLAG_OFF);

    lstm_prep<<<(1024 * KTOT + 255) / 256, 256, 0, stream>>>(
        Wii, Wif, Wig, Wio, Whi, Whf, Whg, Who,
        bii, bif, big, bio, bhi, bhf, bhg, bho,
        wpack, bias, flags);

    lstm_main<<<16, 256, 0, stream>>>(
        x, wpack, bias, (float*)d_out, exch, flags);
}

// Round 4
// 6317.734 us; speedup vs baseline: 1.5924x; 1.5924x over previous
//
#include <hip/hip_runtime.h>

#define INPUT 64
#define HID 256
#define BATCH 128
#define TSTEPS 1000
#define KTOT 320            // 256 (h) + 64 (x)
#define NCH 8               // hidden-dim chunks (blocks per group)

typedef __bf16 bf16_t;
typedef __bf16 bf16x8 __attribute__((ext_vector_type(8)));
typedef float  f32x4  __attribute__((ext_vector_type(4)));

// ---- ws layout (bytes) ----
#define WPACK_OFF   0
#define WPACK_BYTES (1024 * KTOT * 2)            // 655360
#define BIAS_OFF    (WPACK_OFF + WPACK_BYTES)
#define BIAS_BYTES  (1024 * 4)
#define EXCH_OFF    (BIAS_OFF + BIAS_BYTES)      // 64 slots x 2 parity x 512 bf16
#define EXCH_BYTES  (64 * 2 * 512 * 2)           // 131072
#define FLAG_OFF    (EXCH_OFF + EXCH_BYTES)      // 64 flags, 64B apart

__global__ void lstm_prep(
    const float* __restrict__ Wii, const float* __restrict__ Wif,
    const float* __restrict__ Wig, const float* __restrict__ Wio,
    const float* __restrict__ Whi, const float* __restrict__ Whf,
    const float* __restrict__ Whg, const float* __restrict__ Who,
    const float* __restrict__ bii, const float* __restrict__ bif,
    const float* __restrict__ big, const float* __restrict__ bio,
    const float* __restrict__ bhi, const float* __restrict__ bhf,
    const float* __restrict__ bhg, const float* __restrict__ bho,
    bf16_t* __restrict__ wpack, float* __restrict__ bias,
    int* __restrict__ flags)
{
    int id = blockIdx.x * 256 + threadIdx.x;
    if (id < 1024 * KTOT) {
        int n = id / KTOT, k = id % KTOT;
        int g = n >> 8, j = n & 255;
        const float* Wh = (g == 0) ? Whi : (g == 1) ? Whf : (g == 2) ? Whg : Who;
        const float* Wi = (g == 0) ? Wii : (g == 1) ? Wif : (g == 2) ? Wig : Wio;
        float v = (k < HID) ? Wh[j * HID + k] : Wi[j * INPUT + (k - HID)];
        wpack[id] = (bf16_t)v;
    }
    if (id < 1024) {
        int g = id >> 8, j = id & 255;
        const float* bi = (g == 0) ? bii : (g == 1) ? bif : (g == 2) ? big : bio;
        const float* bh = (g == 0) ? bhi : (g == 1) ? bhf : (g == 2) ? bhg : bho;
        bias[id] = bi[j] + bh[j];
    }
    if (id < 64) flags[id * 16] = 0;
}

__device__ __forceinline__ float sigmoid_f(float v) {
    return 1.0f / (1.0f + __expf(-v));
}
__device__ __forceinline__ float tanh_f(float v) {
    return 1.0f - 2.0f / (__expf(2.0f * v) + 1.0f);
}

// 64 blocks x 256 threads. group = bid&7 (XCD), chunk = bid>>3 (32 cols each).
// Wave w computes gate w for the block's 32 cols over all 16 batch rows.
__global__ __launch_bounds__(256) __attribute__((amdgpu_waves_per_eu(1, 1)))
void lstm_main(
    const float* __restrict__ x, const bf16_t* __restrict__ wpack,
    const float* __restrict__ bias_g, float* __restrict__ out,
    bf16_t* __restrict__ exch, int* __restrict__ flags)
{
    __shared__ __align__(16) bf16_t hxx[16 * 328];   // [16 batch][320 K] pad->328
    __shared__ __align__(16) float  gbuf[4 * 16 * 32]; // [gate][16 batch][32 col]

    const int bid   = blockIdx.x;
    const int group = bid & 7;
    const int chunk = bid >> 3;
    const int tid   = threadIdx.x;
    const int w     = tid >> 6;          // wave = gate
    const int l     = tid & 63;
    const int col   = l & 15;
    const int kb    = l >> 4;            // 0..3

    // ---- persistent B frags: 2 ntiles x 10 kslices = 20 frags = 80 VGPRs ----
    bf16x8 bW[2][10];
#pragma unroll
    for (int n = 0; n < 2; ++n) {
        const int jglob = chunk * 32 + n * 16 + col;
        const bf16_t* wrow = wpack + (size_t)(w * 256 + jglob) * KTOT;
#pragma unroll
        for (int ks = 0; ks < 10; ++ks)
            bW[n][ks] = *(const bf16x8*)(wrow + ks * 32 + kb * 8);
    }
#pragma unroll
    for (int n = 0; n < 2; ++n)
#pragma unroll
        for (int ks = 0; ks < 10; ++ks)
            asm volatile("" : "+v"(bW[n][ks]));

    float bias_r[2];
#pragma unroll
    for (int n = 0; n < 2; ++n)
        bias_r[n] = bias_g[w * 256 + chunk * 32 + n * 16 + col];

    // epilogue mapping: thread -> (batch eb, cols ej, ej+1); c-state lives here
    const int eb = tid >> 4;
    const int ej = (tid & 15) * 2;
    float c0 = 0.f, c1 = 0.f;

    // x staging mapping (16 rows x 64 f32 per step, 4 f32/thread)
    const int xrow = tid >> 4;
    const int xi0  = (tid & 15) * 4;
    const float* xbase = x + (size_t)(group * 16 + xrow) * (TSTEPS * INPUT) + xi0;

    // partner-pub read mapping (224 threads: 7 partners x 32B-readers)
    const int pc      = tid >> 5;                    // 0..7 (valid < 7)
    const int inner   = tid & 31;
    const int pchunk  = (chunk + 1 + pc) & 7;
    const int pbid    = pchunk * 8 + group;
    const int prow    = inner >> 1;
    const int pk0     = pchunk * 32 + (inner & 1) * 16;

    int* flag_me = flags + bid * 16;

    // prologue: stage x_0
    {
        float4 v = *(const float4*)(xbase);
        bf16_t* d = &hxx[xrow * 328 + 256 + xi0];
        d[0] = (bf16_t)v.x; d[1] = (bf16_t)v.y; d[2] = (bf16_t)v.z; d[3] = (bf16_t)v.w;
    }
    __syncthreads();

#pragma unroll 1
    for (int t = 0; t < TSTEPS; ++t) {
        // release: pub h_{t-1} written + drained by loop-bottom barrier's vmcnt(0)
        if (tid == 0 && t > 0)
            __hip_atomic_store(flag_me, t, __ATOMIC_RELEASE, __HIP_MEMORY_SCOPE_AGENT);

        // issue x_{t+1} early (consumed in P2)
        float4 xv;
        if (t + 1 < TSTEPS) xv = *(const float4*)(xbase + (size_t)(t + 1) * INPUT);

        f32x4 accA[2], accB[2];
#pragma unroll
        for (int n = 0; n < 2; ++n) {
            accA[n] = (f32x4){bias_r[n], bias_r[n], bias_r[n], bias_r[n]};
            accB[n] = (f32x4){0.f, 0.f, 0.f, 0.f};
        }

        // P1: x MFMAs (ks 8,9) + own-chunk MFMA; partner pubs -> hxx
        {
            bf16x8 ax0 = *(const bf16x8*)(&hxx[col * 328 + 8 * 32 + kb * 8]);
            bf16x8 ax1 = *(const bf16x8*)(&hxx[col * 328 + 9 * 32 + kb * 8]);
#pragma unroll
            for (int n = 0; n < 2; ++n) {
                accA[n] = __builtin_amdgcn_mfma_f32_16x16x32_bf16(ax0, bW[n][8], accA[n], 0, 0, 0);
                accB[n] = __builtin_amdgcn_mfma_f32_16x16x32_bf16(ax1, bW[n][9], accB[n], 0, 0, 0);
            }
        }
        if (t > 0) {
            bf16x8 ao = *(const bf16x8*)(&hxx[col * 328 + chunk * 32 + kb * 8]);
#pragma unroll
            for (int n = 0; n < 2; ++n)
                accA[n] = __builtin_amdgcn_mfma_f32_16x16x32_bf16(ao, bW[n][chunk], accA[n], 0, 0, 0);
            if (tid < 224) {
                while (__hip_atomic_load(flags + pbid * 16, __ATOMIC_ACQUIRE, __HIP_MEMORY_SCOPE_AGENT) < t) {}
                const bf16_t* src = exch + (size_t)(pbid * 2 + ((t - 1) & 1)) * 512 + inner * 16;
                f32x4 v0 = *(const f32x4*)(src);
                f32x4 v1 = *(const f32x4*)(src + 8);
                bf16_t* dst = &hxx[prow * 328 + pk0];
                *(f32x4*)(dst)     = v0;
                *(f32x4*)(dst + 8) = v1;
            }
        }
        __syncthreads();                                   // B1: hxx h_{t-1} complete

        // P2: 7 partner K-slices; stage x_{t+1}; acc -> gbuf
        if (t > 0) {
#pragma unroll
            for (int q = 0; q < 7; ++q) {
                int pks = (chunk + 1 + q) & 7;
                bf16x8 a = *(const bf16x8*)(&hxx[col * 328 + pks * 32 + kb * 8]);
                if (q & 1) {
#pragma unroll
                    for (int n = 0; n < 2; ++n)
                        accB[n] = __builtin_amdgcn_mfma_f32_16x16x32_bf16(a, bW[n][pks], accB[n], 0, 0, 0);
                } else {
#pragma unroll
                    for (int n = 0; n < 2; ++n)
                        accA[n] = __builtin_amdgcn_mfma_f32_16x16x32_bf16(a, bW[n][pks], accA[n], 0, 0, 0);
                }
            }
        }
        if (t + 1 < TSTEPS) {
            bf16_t* d = &hxx[xrow * 328 + 256 + xi0];
            d[0] = (bf16_t)xv.x; d[1] = (bf16_t)xv.y; d[2] = (bf16_t)xv.z; d[3] = (bf16_t)xv.w;
        }
#pragma unroll
        for (int n = 0; n < 2; ++n) {
            f32x4 af = accA[n] + accB[n];
#pragma unroll
            for (int r = 0; r < 4; ++r)
                gbuf[w * 512 + (kb * 4 + r) * 32 + n * 16 + col] = af[r];
        }
        __syncthreads();                                   // B2: gbuf complete

        // P3: epilogue (fixed thread<->(b,j) ownership; c in regs)
        {
            float2 gi = *(const float2*)&gbuf[0 * 512 + eb * 32 + ej];
            float2 gf = *(const float2*)&gbuf[1 * 512 + eb * 32 + ej];
            float2 gg = *(const float2*)&gbuf[2 * 512 + eb * 32 + ej];
            float2 go = *(const float2*)&gbuf[3 * 512 + eb * 32 + ej];
            c0 = sigmoid_f(gf.x) * c0 + sigmoid_f(gi.x) * tanh_f(gg.x);
            c1 = sigmoid_f(gf.y) * c1 + sigmoid_f(gi.y) * tanh_f(gg.y);
            float h0 = sigmoid_f(go.x) * tanh_f(c0);
            float h1 = sigmoid_f(go.y) * tanh_f(c1);
            bf16_t h0b = (bf16_t)h0, h1b = (bf16_t)h1;
            // own cols of hxx for next step
            hxx[eb * 328 + chunk * 32 + ej]     = h0b;
            hxx[eb * 328 + chunk * 32 + ej + 1] = h1b;
            // publish for partners
            bf16_t* pw = exch + (size_t)(bid * 2 + (t & 1)) * 512 + eb * 32 + ej;
            pw[0] = h0b; pw[1] = h1b;
            // output
            const int bg = group * 16 + eb;
            const int jg = chunk * 32 + ej;
            *(float2*)&out[((size_t)bg * TSTEPS + t) * HID + jg] = make_float2(h0, h1);
            if (t == TSTEPS - 1) {
                float* hn = out + (size_t)BATCH * TSTEPS * HID;
                float* cn = hn + (size_t)BATCH * HID;
                *(float2*)&hn[(size_t)bg * HID + jg] = make_float2(h0, h1);
                *(float2*)&cn[(size_t)bg * HID + jg] = make_float2(c0, c1);
            }
        }
        __syncthreads();                                   // B0: drains pub/out stores
    }
}

extern "C" void kernel_launch(void* const* d_in, const int* in_sizes, int n_in,
                              void* d_out, int out_size, void* d_ws, size_t ws_size,
                              hipStream_t stream)
{
    (void)in_sizes; (void)n_in; (void)out_size; (void)ws_size;
    const float* x   = (const float*)d_in[0];
    const float* Wii = (const float*)d_in[1];
    const float* bii = (const float*)d_in[2];
    const float* Wif = (const float*)d_in[3];
    const float* bif = (const float*)d_in[4];
    const float* Wig = (const float*)d_in[5];
    const float* big = (const float*)d_in[6];
    const float* Wio = (const float*)d_in[7];
    const float* bio = (const float*)d_in[8];
    const float* Whi = (const float*)d_in[9];
    const float* bhi = (const float*)d_in[10];
    const float* Whf = (const float*)d_in[11];
    const float* bhf = (const float*)d_in[12];
    const float* Whg = (const float*)d_in[13];
    const float* bhg = (const float*)d_in[14];
    const float* Who = (const float*)d_in[15];
    const float* bho = (const float*)d_in[16];

    char* ws = (char*)d_ws;
    bf16_t* wpack = (bf16_t*)(ws + WPACK_OFF);
    float*  bias  = (float*)(ws + BIAS_OFF);
    bf16_t* exch  = (bf16_t*)(ws + EXCH_OFF);
    int*    flags = (int*)(ws + FLAG_OFF);

    lstm_prep<<<(1024 * KTOT + 255) / 256, 256, 0, stream>>>(
        Wii, Wif, Wig, Wio, Whi, Whf, Whg, Who,
        bii, bif, big, bio, bhi, bhf, bhg, bho,
        wpack, bias, flags);

    lstm_main<<<64, 256, 0, stream>>>(
        x, wpack, bias, (float*)d_out, exch, flags);
}

// Round 5
// 3120.153 us; speedup vs baseline: 3.2244x; 2.0248x over previous
//
#include <hip/hip_runtime.h>

#define INPUT 64
#define HID 256
#define BATCH 128
#define TSTEPS 1000
#define KTOT 320            // 256 (h) + 64 (x)

typedef __bf16 bf16_t;
typedef __bf16 bf16x8 __attribute__((ext_vector_type(8)));
typedef float  f32x4  __attribute__((ext_vector_type(4)));

// ---- ws layout (bytes) ----
#define WPACK_OFF   0
#define WPACK_BYTES (1024 * KTOT * 2)            // 655360
#define BIAS_OFF    (WPACK_OFF + WPACK_BYTES)
#define BIAS_BYTES  (1024 * 4)
#define EXCH_OFF    (BIAS_OFF + BIAS_BYTES)      // 64 slots x 2 parity x 512 bf16
#define EXCH_BYTES  (64 * 2 * 512 * 2)           // 131072
#define FLAG_OFF    (EXCH_OFF + EXCH_BYTES)      // 64 flags, 64B apart

__global__ void lstm_prep(
    const float* __restrict__ Wii, const float* __restrict__ Wif,
    const float* __restrict__ Wig, const float* __restrict__ Wio,
    const float* __restrict__ Whi, const float* __restrict__ Whf,
    const float* __restrict__ Whg, const float* __restrict__ Who,
    const float* __restrict__ bii, const float* __restrict__ bif,
    const float* __restrict__ big, const float* __restrict__ bio,
    const float* __restrict__ bhi, const float* __restrict__ bhf,
    const float* __restrict__ bhg, const float* __restrict__ bho,
    bf16_t* __restrict__ wpack, float* __restrict__ bias,
    int* __restrict__ flags)
{
    int id = blockIdx.x * 256 + threadIdx.x;
    if (id < 1024 * KTOT) {
        int n = id / KTOT, k = id % KTOT;
        int g = n >> 8, j = n & 255;
        const float* Wh = (g == 0) ? Whi : (g == 1) ? Whf : (g == 2) ? Whg : Who;
        const float* Wi = (g == 0) ? Wii : (g == 1) ? Wif : (g == 2) ? Wig : Wio;
        float v = (k < HID) ? Wh[j * HID + k] : Wi[j * INPUT + (k - HID)];
        wpack[id] = (bf16_t)v;
    }
    if (id < 1024) {
        int g = id >> 8, j = id & 255;
        const float* bi = (g == 0) ? bii : (g == 1) ? bif : (g == 2) ? big : bio;
        const float* bh = (g == 0) ? bhi : (g == 1) ? bhf : (g == 2) ? bhg : bho;
        bias[id] = bi[j] + bh[j];
    }
    if (id < 64)
        __hip_atomic_store(flags + id * 16, 0, __ATOMIC_RELAXED, __HIP_MEMORY_SCOPE_AGENT);
}

__device__ __forceinline__ float sigmoid_f(float v) {
    return 1.0f / (1.0f + __expf(-v));
}
__device__ __forceinline__ float tanh_f(float v) {
    return 1.0f - 2.0f / (__expf(2.0f * v) + 1.0f);
}

// 64 blocks x 256 threads. group = bid&7 (XCD), chunk = bid>>3 (32 cols each).
// Wave w computes gate w for the block's 32 cols over all 16 batch rows.
__global__ __launch_bounds__(256) __attribute__((amdgpu_waves_per_eu(1, 1)))
void lstm_main(
    const float* __restrict__ x, const bf16_t* __restrict__ wpack,
    const float* __restrict__ bias_g, float* __restrict__ out,
    bf16_t* __restrict__ exch, int* __restrict__ flags)
{
    __shared__ __align__(16) bf16_t hxx[16 * 328];     // [16 batch][320 K] pad->328
    __shared__ __align__(16) float  gbuf[4 * 16 * 34]; // [gate][16 batch][32 col] pad->34

    const int bid   = blockIdx.x;
    const int group = bid & 7;
    const int chunk = bid >> 3;
    const int tid   = threadIdx.x;
    const int w     = tid >> 6;          // wave = gate
    const int l     = tid & 63;
    const int col   = l & 15;
    const int kb    = l >> 4;            // 0..3

    // ---- persistent B frags: 2 ntiles x 10 kslices = 20 frags = 80 VGPRs ----
    bf16x8 bW[2][10];
#pragma unroll
    for (int n = 0; n < 2; ++n) {
        const int jglob = chunk * 32 + n * 16 + col;
        const bf16_t* wrow = wpack + (size_t)(w * 256 + jglob) * KTOT;
#pragma unroll
        for (int ks = 0; ks < 10; ++ks)
            bW[n][ks] = *(const bf16x8*)(wrow + ks * 32 + kb * 8);
    }
#pragma unroll
    for (int n = 0; n < 2; ++n)
#pragma unroll
        for (int ks = 0; ks < 10; ++ks)
            asm volatile("" : "+v"(bW[n][ks]));

    float bias_r[2];
#pragma unroll
    for (int n = 0; n < 2; ++n)
        bias_r[n] = bias_g[w * 256 + chunk * 32 + n * 16 + col];

    // epilogue mapping: thread -> (batch eb, cols ej, ej+1); c-state lives here
    const int eb = tid >> 4;
    const int ej = (tid & 15) * 2;
    float c0 = 0.f, c1 = 0.f;

    // x staging mapping (16 rows x 64 f32 per step, 4 f32/thread)
    const int xrow = tid >> 4;
    const int xi0  = (tid & 15) * 4;
    const float* xbase = x + (size_t)(group * 16 + xrow) * (TSTEPS * INPUT) + xi0;

    // partner-pub read mapping (224 threads: 7 partners x 32B-readers)
    const int pc      = tid >> 5;                    // 0..7 (valid < 7)
    const int inner   = tid & 31;
    const int pchunk  = (chunk + 1 + pc) & 7;
    const int pbid    = pchunk * 8 + group;
    const int prow    = inner >> 1;
    const int pk0     = pchunk * 32 + (inner & 1) * 16;

    int* flag_me = flags + bid * 16;
    const int* flag_pn = flags + pbid * 16;

    // prologue: stage x_0
    {
        float4 v = *(const float4*)(xbase);
        bf16_t* d = &hxx[xrow * 328 + 256 + xi0];
        d[0] = (bf16_t)v.x; d[1] = (bf16_t)v.y; d[2] = (bf16_t)v.z; d[3] = (bf16_t)v.w;
    }
    __syncthreads();

#pragma unroll 1
    for (int t = 0; t < TSTEPS; ++t) {
        const int par = t & 1;

        // issue x_{t+1} early (consumed in P2)
        float4 xv;
        if (t + 1 < TSTEPS) xv = *(const float4*)(xbase + (size_t)(t + 1) * INPUT);

        f32x4 accA[2], accB[2];
#pragma unroll
        for (int n = 0; n < 2; ++n) {
            accA[n] = (f32x4){bias_r[n], bias_r[n], bias_r[n], bias_r[n]};
            accB[n] = (f32x4){0.f, 0.f, 0.f, 0.f};
        }

        // P1: x MFMAs (ks 8,9) + own-chunk MFMA; then spin + pub reads -> hxx
        {
            bf16x8 ax0 = *(const bf16x8*)(&hxx[col * 328 + 8 * 32 + kb * 8]);
            bf16x8 ax1 = *(const bf16x8*)(&hxx[col * 328 + 9 * 32 + kb * 8]);
#pragma unroll
            for (int n = 0; n < 2; ++n) {
                accA[n] = __builtin_amdgcn_mfma_f32_16x16x32_bf16(ax0, bW[n][8], accA[n], 0, 0, 0);
                accB[n] = __builtin_amdgcn_mfma_f32_16x16x32_bf16(ax1, bW[n][9], accB[n], 0, 0, 0);
            }
        }
        if (t > 0) {
            bf16x8 ao = *(const bf16x8*)(&hxx[col * 328 + chunk * 32 + kb * 8]);
#pragma unroll
            for (int n = 0; n < 2; ++n)
                accA[n] = __builtin_amdgcn_mfma_f32_16x16x32_bf16(ao, bW[n][chunk], accA[n], 0, 0, 0);
            if (tid < 224) {
                // relaxed poll: no acquire fence -> no buffer_inv storm
                while (__hip_atomic_load(flag_pn, __ATOMIC_RELAXED, __HIP_MEMORY_SCOPE_AGENT) < t) {}
                // data via sc0 (bypass L1, served by the shared same-XCD L2)
                const bf16_t* src = exch + (size_t)(pbid * 2 + ((t - 1) & 1)) * 512 + inner * 16;
                f32x4 v0, v1;
                asm volatile(
                    "global_load_dwordx4 %0, %2, off sc0\n\t"
                    "global_load_dwordx4 %1, %3, off sc0\n\t"
                    "s_waitcnt vmcnt(0)"
                    : "=&v"(v0), "=&v"(v1)
                    : "v"(src), "v"(src + 8)
                    : "memory");
                bf16_t* dst = &hxx[prow * 328 + pk0];
                *(f32x4*)(dst)     = v0;
                *(f32x4*)(dst + 8) = v1;
            }
        }
        __syncthreads();                                   // B1: hxx h_{t-1} complete

        // P2: 7 partner K-slices; stage x_{t+1}; acc -> gbuf
        if (t > 0) {
#pragma unroll
            for (int q = 0; q < 7; ++q) {
                int pks = (chunk + 1 + q) & 7;
                bf16x8 a = *(const bf16x8*)(&hxx[col * 328 + pks * 32 + kb * 8]);
                if (q & 1) {
#pragma unroll
                    for (int n = 0; n < 2; ++n)
                        accB[n] = __builtin_amdgcn_mfma_f32_16x16x32_bf16(a, bW[n][pks], accB[n], 0, 0, 0);
                } else {
#pragma unroll
                    for (int n = 0; n < 2; ++n)
                        accA[n] = __builtin_amdgcn_mfma_f32_16x16x32_bf16(a, bW[n][pks], accA[n], 0, 0, 0);
                }
            }
        }
        if (t + 1 < TSTEPS) {
            bf16_t* d = &hxx[xrow * 328 + 256 + xi0];
            d[0] = (bf16_t)xv.x; d[1] = (bf16_t)xv.y; d[2] = (bf16_t)xv.z; d[3] = (bf16_t)xv.w;
        }
#pragma unroll
        for (int n = 0; n < 2; ++n) {
            f32x4 af = accA[n] + accB[n];
#pragma unroll
            for (int r = 0; r < 4; ++r)
                gbuf[w * 544 + (kb * 4 + r) * 34 + n * 16 + col] = af[r];
        }
        __syncthreads();                                   // B2: gbuf complete

        // P3: epilogue (fixed thread<->(b,j) ownership; c in regs)
        float h0, h1;
        {
            float2 gi = *(const float2*)&gbuf[0 * 544 + eb * 34 + ej];
            float2 gf = *(const float2*)&gbuf[1 * 544 + eb * 34 + ej];
            float2 gg = *(const float2*)&gbuf[2 * 544 + eb * 34 + ej];
            float2 go = *(const float2*)&gbuf[3 * 544 + eb * 34 + ej];
            c0 = sigmoid_f(gf.x) * c0 + sigmoid_f(gi.x) * tanh_f(gg.x);
            c1 = sigmoid_f(gf.y) * c1 + sigmoid_f(gi.y) * tanh_f(gg.y);
            h0 = sigmoid_f(go.x) * tanh_f(c0);
            h1 = sigmoid_f(go.y) * tanh_f(c1);
            bf16_t h0b = (bf16_t)h0, h1b = (bf16_t)h1;
            // own cols of hxx for next step
            hxx[eb * 328 + chunk * 32 + ej]     = h0b;
            hxx[eb * 328 + chunk * 32 + ej + 1] = h1b;
            // publish for partners (plain stores -> same-XCD L2)
            bf16_t* pw = exch + (size_t)(bid * 2 + par) * 512 + eb * 32 + ej;
            pw[0] = h0b; pw[1] = h1b;
        }
        __syncthreads();                // B0: vmcnt(0) drains pub stores into L2
        if (tid == 0)
            __hip_atomic_store(flag_me, t + 1, __ATOMIC_RELAXED, __HIP_MEMORY_SCOPE_AGENT);

        // out stores AFTER the release (drain overlaps next step's spin)
        {
            const int bg = group * 16 + eb;
            const int jg = chunk * 32 + ej;
            *(float2*)&out[((size_t)bg * TSTEPS + t) * HID + jg] = make_float2(h0, h1);
            if (t == TSTEPS - 1) {
                float* hn = out + (size_t)BATCH * TSTEPS * HID;
                float* cn = hn + (size_t)BATCH * HID;
                *(float2*)&hn[(size_t)bg * HID + jg] = make_float2(h0, h1);
                *(float2*)&cn[(size_t)bg * HID + jg] = make_float2(c0, c1);
            }
        }
    }
}

extern "C" void kernel_launch(void* const* d_in, const int* in_sizes, int n_in,
                              void* d_out, int out_size, void* d_ws, size_t ws_size,
                              hipStream_t stream)
{
    (void)in_sizes; (void)n_in; (void)out_size; (void)ws_size;
    const float* x   = (const float*)d_in[0];
    const float* Wii = (const float*)d_in[1];
    const float* bii = (const float*)d_in[2];
    const float* Wif = (const float*)d_in[3];
    const float* bif = (const float*)d_in[4];
    const float* Wig = (const float*)d_in[5];
    const float* big = (const float*)d_in[6];
    const float* Wio = (const float*)d_in[7];
    const float* bio = (const float*)d_in[8];
    const float* Whi = (const float*)d_in[9];
    const float* bhi = (const float*)d_in[10];
    const float* Whf = (const float*)d_in[11];
    const float* bhf = (const float*)d_in[12];
    const float* Whg = (const float*)d_in[13];
    const float* bhg = (const float*)d_in[14];
    const float* Who = (const float*)d_in[15];
    const float* bho = (const float*)d_in[16];

    char* ws = (char*)d_ws;
    bf16_t* wpack = (bf16_t*)(ws + WPACK_OFF);
    float*  bias  = (float*)(ws + BIAS_OFF);
    bf16_t* exch  = (bf16_t*)(ws + EXCH_OFF);
    int*    flags = (int*)(ws + FLAG_OFF);

    lstm_prep<<<(1024 * KTOT + 255) / 256, 256, 0, stream>>>(
        Wii, Wif, Wig, Wio, Whi, Whf, Whg, Who,
        bii, bif, big, bio, bhi, bhf, bhg, bho,
        wpack, bias, flags);

    lstm_main<<<64, 256, 0, stream>>>(
        x, wpack, bias, (float*)d_out, exch, flags);
}

// Round 7
// 2625.836 us; speedup vs baseline: 3.8314x; 1.1883x over previous
//
#include <hip/hip_runtime.h>

#define INPUT 64
#define HID 256
#define BATCH 128
#define TSTEPS 1000
#define KTOT 320            // 256 (h) + 64 (x)

typedef __bf16 bf16_t;
typedef __bf16 bf16x8 __attribute__((ext_vector_type(8)));
typedef float  f32x4  __attribute__((ext_vector_type(4)));

// ---- ws layout (bytes) ----
#define WPACK_OFF   0
#define WPACK_BYTES (1024 * KTOT * 2)            // 655360
#define BIAS_OFF    (WPACK_OFF + WPACK_BYTES)
#define BIAS_BYTES  (1024 * 4)
#define EXCH_OFF    (BIAS_OFF + BIAS_BYTES)      // 16 blocks x 2 parity x 2048 bf16
#define EXCH_BYTES  (16 * 2 * 2048 * 2)          // 131072
#define FLAG_OFF    (EXCH_OFF + EXCH_BYTES)      // 16 flags, 256B apart

__global__ void lstm_prep(
    const float* __restrict__ Wii, const float* __restrict__ Wif,
    const float* __restrict__ Wig, const float* __restrict__ Wio,
    const float* __restrict__ Whi, const float* __restrict__ Whf,
    const float* __restrict__ Whg, const float* __restrict__ Who,
    const float* __restrict__ bii, const float* __restrict__ bif,
    const float* __restrict__ big, const float* __restrict__ bio,
    const float* __restrict__ bhi, const float* __restrict__ bhf,
    const float* __restrict__ bhg, const float* __restrict__ bho,
    bf16_t* __restrict__ wpack, float* __restrict__ bias,
    int* __restrict__ flags)
{
    int id = blockIdx.x * 256 + threadIdx.x;
    if (id < 1024 * KTOT) {
        int n = id / KTOT, k = id % KTOT;
        int g = n >> 8, j = n & 255;
        const float* Wh = (g == 0) ? Whi : (g == 1) ? Whf : (g == 2) ? Whg : Who;
        const float* Wi = (g == 0) ? Wii : (g == 1) ? Wif : (g == 2) ? Wig : Wio;
        float v = (k < HID) ? Wh[j * HID + k] : Wi[j * INPUT + (k - HID)];
        wpack[id] = (bf16_t)v;
    }
    if (id < 1024) {
        int g = id >> 8, j = id & 255;
        const float* bi = (g == 0) ? bii : (g == 1) ? bif : (g == 2) ? big : bio;
        const float* bh = (g == 0) ? bhi : (g == 1) ? bhf : (g == 2) ? bhg : bho;
        bias[id] = bi[j] + bh[j];
    }
    if (id < 16)
        __hip_atomic_store(flags + id * 64, 0, __ATOMIC_RELAXED, __HIP_MEMORY_SCOPE_AGENT);
}

__device__ __forceinline__ float sigmoid_f(float v) {
    return 1.0f / (1.0f + __expf(-v));
}
__device__ __forceinline__ float tanh_f(float v) {
    return 1.0f - 2.0f / (__expf(2.0f * v) + 1.0f);
}

// 16 blocks x 512 threads. group = bid&7 (same XCD for the pair), half = bid>>3.
// Wave w (0..7) owns cols [w*16, w*16+16) of the half, ALL 4 gates:
// 4 x 10 = 40 weight frags = 160 VGPRs -> in-register epilogue, 2 barriers/step.
__global__ __launch_bounds__(512) void lstm_main(
    const float* __restrict__ x, const bf16_t* __restrict__ wpack,
    const float* __restrict__ bias_g, float* __restrict__ out,
    bf16_t* __restrict__ exch, int* __restrict__ flags)
{
    // [parity][16 rows][328 bf16]: K 0..255 = h (both halves), 256..319 = x.
    // pad 320->328 (round-5-proven layout, no swizzle).
    __shared__ __align__(16) bf16_t hxx[2][16 * 328];

    const int bid   = blockIdx.x;
    const int group = bid & 7;
    const int half  = bid >> 3;
    const int tid   = threadIdx.x;
    const int w     = tid >> 6;          // wave 0..7
    const int l     = tid & 63;
    const int col   = l & 15;
    const int kb    = l >> 4;            // 0..3

    const int jloc  = w * 16 + col;            // 0..127 within half
    const int jglob = half * 128 + jloc;       // 0..255

    // ---- persistent weights: 4 gates x 10 kslices = 40 frags = 160 VGPRs ----
    bf16x8 bW[4][10];
#pragma unroll
    for (int g = 0; g < 4; ++g) {
        const bf16_t* wrow = wpack + (size_t)(g * 256 + jglob) * KTOT;
#pragma unroll
        for (int ks = 0; ks < 10; ++ks)
            bW[g][ks] = *(const bf16x8*)(wrow + ks * 32 + kb * 8);
    }
#pragma unroll
    for (int g = 0; g < 4; ++g)
#pragma unroll
        for (int ks = 0; ks < 10; ++ks)
            asm volatile("" : "+v"(bW[g][ks]));

    float bias_r[4];
#pragma unroll
    for (int g = 0; g < 4; ++g)
        bias_r[g] = bias_g[g * 256 + jglob];

    float c_st[4] = {0.f, 0.f, 0.f, 0.f};

    const int pbid = (1 - half) * 8 + group;
    int*       flag_me = flags + bid * 64;
    const int* flag_pn = flags + pbid * 64;
    const int  pbase   = (1 - half) * 128;     // partner cols in hxx (elements)

    // x staging: thread -> (row xb = tid>>5, 2 f32 at xi)
    const int xb = tid >> 5;
    const int xi = (tid & 31) * 2;
    const float* xbase = x + (size_t)(group * 16 + xb) * (TSTEPS * INPUT) + xi;

    // partner fetch: thread -> (row prow, 4 bf16 at pe0)
    const int prow = tid >> 5;
    const int pe0  = (tid & 31) * 4;

    // prologue: x_0 -> hxx[0], x_1 -> regs
    {
        float2 v = *(const float2*)(xbase);
        hxx[0][xb * 328 + 256 + xi]     = (bf16_t)v.x;
        hxx[0][xb * 328 + 256 + xi + 1] = (bf16_t)v.y;
    }
    float2 xv = *(const float2*)(xbase + INPUT);
    __syncthreads();

#pragma unroll 1
    for (int t = 0; t < TSTEPS; ++t) {
        const int cur = t & 1;
        const int nxt = cur ^ 1;

        // ---- P1: stage x_{t+1} -> hxx[nxt]; fetch partner h_{t-1} -> hxx[cur]
        if (t + 1 < TSTEPS) {
            hxx[nxt][xb * 328 + 256 + xi]     = (bf16_t)xv.x;
            hxx[nxt][xb * 328 + 256 + xi + 1] = (bf16_t)xv.y;
        }
        if (t + 2 < TSTEPS)
            xv = *(const float2*)(xbase + (size_t)(t + 2) * INPUT);
        if (t > 0) {
            if (l == 0) {
                while (__hip_atomic_load(flag_pn, __ATOMIC_RELAXED, __HIP_MEMORY_SCOPE_AGENT) < t) {}
            }
            const bf16_t* src = exch + ((size_t)pbid * 2 + ((t - 1) & 1)) * 2048
                              + prow * 128 + pe0;
            float2 v;
            asm volatile(
                "global_load_dwordx2 %0, %1, off sc0\n\t"
                "s_waitcnt vmcnt(0)"
                : "=&v"(v) : "v"(src) : "memory");
            *(float2*)&hxx[cur][prow * 328 + pbase + pe0] = v;
        }
        __syncthreads();                                   // B1: hxx[cur] complete

        // ---- P2: 40 MFMAs, weights resident ----
        f32x4 acc[4];
#pragma unroll
        for (int g = 0; g < 4; ++g)
            acc[g] = (f32x4){bias_r[g], bias_r[g], bias_r[g], bias_r[g]};

        const bf16_t* arow = &hxx[cur][col * 328 + kb * 8];
        {
            bf16x8 a8 = *(const bf16x8*)(arow + 8 * 32);
            bf16x8 a9 = *(const bf16x8*)(arow + 9 * 32);
#pragma unroll
            for (int g = 0; g < 4; ++g) {
                acc[g] = __builtin_amdgcn_mfma_f32_16x16x32_bf16(a8, bW[g][8], acc[g], 0, 0, 0);
                acc[g] = __builtin_amdgcn_mfma_f32_16x16x32_bf16(a9, bW[g][9], acc[g], 0, 0, 0);
            }
        }
        if (t > 0) {
#pragma unroll
            for (int ks = 0; ks < 8; ++ks) {
                bf16x8 a = *(const bf16x8*)(arow + ks * 32);
#pragma unroll
                for (int g = 0; g < 4; ++g)
                    acc[g] = __builtin_amdgcn_mfma_f32_16x16x32_bf16(a, bW[g][ks], acc[g], 0, 0, 0);
            }
        }

        // ---- P3: in-register epilogue; h -> hxx[nxt] own cols + pub ----
        bf16_t* pub = exch + ((size_t)bid * 2 + cur) * 2048;
        float hv[4];
#pragma unroll
        for (int r = 0; r < 4; ++r) {
            float gi = sigmoid_f(acc[0][r]);
            float gf = sigmoid_f(acc[1][r]);
            float gg = tanh_f(acc[2][r]);
            float go = sigmoid_f(acc[3][r]);
            float c  = gf * c_st[r] + gi * gg;
            c_st[r]  = c;
            float h  = go * tanh_f(c);
            hv[r]    = h;
            bf16_t hb = (bf16_t)h;
            const int row = kb * 4 + r;
            hxx[nxt][row * 328 + jglob] = hb;              // own A for next step
            pub[row * 128 + jloc]       = hb;              // partner's A for next step
        }
        __syncthreads();                                   // B0: pub stores drained
        if (tid == 0)
            __hip_atomic_store(flag_me, t + 1, __ATOMIC_RELAXED, __HIP_MEMORY_SCOPE_AGENT);

        // out stores AFTER release (drain overlaps next step's spin)
#pragma unroll
        for (int r = 0; r < 4; ++r) {
            const int row = kb * 4 + r;
            const int bg  = group * 16 + row;
            out[((size_t)bg * TSTEPS + t) * HID + jglob] = hv[r];
        }
        if (t == TSTEPS - 1) {
            float* hn = out + (size_t)BATCH * TSTEPS * HID;
            float* cn = hn + (size_t)BATCH * HID;
#pragma unroll
            for (int r = 0; r < 4; ++r) {
                const int row = kb * 4 + r;
                const int bg  = group * 16 + row;
                hn[(size_t)bg * HID + jglob] = hv[r];
                cn[(size_t)bg * HID + jglob] = c_st[r];
            }
        }
    }
}

extern "C" void kernel_launch(void* const* d_in, const int* in_sizes, int n_in,
                              void* d_out, int out_size, void* d_ws, size_t ws_size,
                              hipStream_t stream)
{
    (void)in_sizes; (void)n_in; (void)out_size; (void)ws_size;
    const float* x   = (const float*)d_in[0];
    const float* Wii = (const float*)d_in[1];
    const float* bii = (const float*)d_in[2];
    const float* Wif = (const float*)d_in[3];
    const float* bif = (const float*)d_in[4];
    const float* Wig = (const float*)d_in[5];
    const float* big = (const float*)d_in[6];
    const float* Wio = (const float*)d_in[7];
    const float* bio = (const float*)d_in[8];
    const float* Whi = (const float*)d_in[9];
    const float* bhi = (const float*)d_in[10];
    const float* Whf = (const float*)d_in[11];
    const float* bhf = (const float*)d_in[12];
    const float* Whg = (const float*)d_in[13];
    const float* bhg = (const float*)d_in[14];
    const float* Who = (const float*)d_in[15];
    const float* bho = (const float*)d_in[16];

    char* ws = (char*)d_ws;
    bf16_t* wpack = (bf16_t*)(ws + WPACK_OFF);
    float*  bias  = (float*)(ws + BIAS_OFF);
    bf16_t* exch  = (bf16_t*)(ws + EXCH_OFF);
    int*    flags = (int*)(ws + FLAG_OFF);

    lstm_prep<<<(1024 * KTOT + 255) / 256, 256, 0, stream>>>(
        Wii, Wif, Wig, Wio, Whi, Whf, Whg, Who,
        bii, bif, big, bio, bhi, bhf, bhg, bho,
        wpack, bias, flags);

    lstm_main<<<16, 512, 0, stream>>>(
        x, wpack, bias, (float*)d_out, exch, flags);
}